// Round 1
// baseline (458.556 us; speedup 1.0000x reference)
//
#include <hip/hip_runtime.h>

#define NT 32768
#define DI 36
#define HH 64
#define G3 192
#define LH 20

__device__ __forceinline__ float readlane_f(float v, int l) {
    union { float f; int i; } u;
    u.f = v;
    u.i = __builtin_amdgcn_readlane(u.i, l);
    return u.f;
}

__device__ __forceinline__ float sigmoid_f(float x) {
    return 1.f / (1.f + __expf(-x));
}
// tanh(x) = 1 - 2/(1+e^{2x}); overflow-safe: e^inf -> inf -> 1, e^-inf -> 0 -> -1
__device__ __forceinline__ float tanh_f(float x) {
    return 1.f - 2.f / (1.f + __expf(2.f * x));
}

// Kernel 1: gi[t][j] = emb[t,:] . W_ih[j,:] + b_ih[j] + (j<128 ? b_hh[j] : 0)
// (b_hh for r,z gates folds into gi; n-gate b_hh must stay separate because the
//  reference computes tanh(inn + r*(hnn + b_hh_n)).)
// Also transposes W1 -> W1T for the main kernel's MLP.
__global__ __launch_bounds__(192) void prep_kernel(
    const float* __restrict__ emb, const float* __restrict__ W_ih,
    const float* __restrict__ b_ih, const float* __restrict__ b_hh,
    const float* __restrict__ W1,
    float* __restrict__ gi, float* __restrict__ W1T)
{
    __shared__ float Wt[DI][G3 + 1];   // +1 pad: conflict-free column reads
    __shared__ float Et[DI][HH + 4];   // +4 pad: keeps rows 16B-aligned
    const int tid = threadIdx.x;
    const int t0 = blockIdx.x * 64;

    for (int i = tid; i < G3 * DI; i += 192)
        Wt[i % DI][i / DI] = W_ih[i];
    for (int i = tid; i < 64 * DI; i += 192)
        Et[i % DI][i / DI] = emb[(size_t)(t0 + i / DI) * DI + (i % DI)];
    if (blockIdx.x == 0) {
        for (int i = tid; i < HH * HH; i += 192)
            W1T[(i & 63) * HH + (i >> 6)] = W1[i];
    }
    __syncthreads();

    float acc[64];
#pragma unroll
    for (int i = 0; i < 64; ++i) acc[i] = 0.f;
    for (int k = 0; k < DI; ++k) {
        const float w = Wt[k][tid];        // j = tid, conflict-free
#pragma unroll
        for (int i = 0; i < 64; ++i)
            acc[i] = fmaf(Et[k][i], w, acc[i]);   // broadcast b128 reads
    }
    const float bias = b_ih[tid] + (tid < 128 ? b_hh[tid] : 0.f);
    for (int i = 0; i < 64; ++i)
        gi[(size_t)(t0 + i) * G3 + tid] = acc[i] + bias;   // coalesced
}

// Kernel 2: per-t sliding-window GRU + MLP.
// Block = 512 threads (8 waves), 128 t's per block, grid = 256 (1 block/CU).
// Wave tt handles t in [T0+16*tt, T0+16*tt+16); lane j holds h[t][j] (16 regs).
// k-loop: h[t][k] broadcast via v_readlane (same wave), W_hh^T from LDS.
// No barriers inside the 20-step loop; waves are independent.
__global__ __launch_bounds__(512) void gru_kernel(
    const float* __restrict__ gi, const float* __restrict__ W_hh,
    const float* __restrict__ b_hh, const float* __restrict__ b1,
    const float* __restrict__ W2, const float* __restrict__ b2,
    const float* __restrict__ W1T, const int* __restrict__ dones,
    float* __restrict__ out)
{
    __shared__ float Wt[HH * 194];   // W_hh transposed [k][j], stride 194 (bank (2k+j))
    __shared__ int sfirst[128];
    const int tid = threadIdx.x;
    const int lane = tid & 63;
    const int tt = tid >> 6;
    const int T0 = blockIdx.x * 128;
    const int tl0 = tt * 16;

    // Stage W_hh^T: consecutive i -> consecutive k -> banks stride 2 (4-way, one-time)
    for (int i = tid; i < G3 * HH; i += 512) {
        const int j = i >> 6, k = i & 63;
        Wt[k * 194 + j] = W_hh[i];
    }
    // win_start is local: window <= 20, so only dones[t-19..t-1] matter.
    if (tid < 128) {
        const int t = T0 + tid;
        int lo = t - (LH - 1); if (lo < 0) lo = 0;
        int ws = lo;
        for (int j = t - 1; j >= lo; --j)
            if (dones[j] != 0) { ws = j + 1; break; }
        sfirst[tid] = ws - (t - (LH - 1));   // first valid window step s
    }
    __syncthreads();

    const float bn = b_hh[128 + lane];
    int sfr[16];
    float h[16];
#pragma unroll
    for (int i = 0; i < 16; ++i) { h[i] = 0.f; sfr[i] = sfirst[tl0 + i]; }

    for (int s = 0; s < LH; ++s) {
        // Prefetch gi for this step (issued before k-loop; hides L2 latency)
        float gr[16], gz[16], gn[16];
#pragma unroll
        for (int i = 0; i < 16; ++i) {
            int g = T0 + tl0 + i - (LH - 1) + s;
            g = g < 0 ? 0 : g;                       // masked anyway when invalid
            const float* p = gi + (size_t)g * G3 + lane;
            gr[i] = p[0]; gz[i] = p[64]; gn[i] = p[128];
        }
        float ar[16], az[16], an[16];
#pragma unroll
        for (int i = 0; i < 16; ++i) { ar[i] = 0.f; az[i] = 0.f; an[i] = 0.f; }
#pragma unroll 4
        for (int k = 0; k < HH; ++k) {
            const float wr = Wt[k * 194 + lane];          // conflict-free
            const float wz = Wt[k * 194 + 64 + lane];
            const float wn = Wt[k * 194 + 128 + lane];
#pragma unroll
            for (int i = 0; i < 16; ++i) {
                const float hv = readlane_f(h[i], k);     // h[t][k] from lane k
                ar[i] = fmaf(hv, wr, ar[i]);
                az[i] = fmaf(hv, wz, az[i]);
                an[i] = fmaf(hv, wn, an[i]);
            }
        }
#pragma unroll
        for (int i = 0; i < 16; ++i) {
            const float r  = sigmoid_f(ar[i] + gr[i]);
            const float z  = sigmoid_f(az[i] + gz[i]);
            const float nc = tanh_f(gn[i] + r * (an[i] + bn));
            const float hn = fmaf(z, h[i] - nc, nc);      // (1-z)*nc + z*h
            h[i] = (s >= sfr[i]) ? hn : h[i];             // window-validity mask
        }
    }

    // MLP layer 1: hid[t][m] = relu(b1[m] + sum_k W1[m][k] h[t][k]), m = lane
    float a1[16];
#pragma unroll
    for (int i = 0; i < 16; ++i) a1[i] = 0.f;
    for (int k = 0; k < HH; ++k) {
        const float w = W1T[k * HH + lane];   // coalesced, L1-resident 16KB
#pragma unroll
        for (int i = 0; i < 16; ++i)
            a1[i] = fmaf(readlane_f(h[i], k), w, a1[i]);
    }
    const float bb1 = b1[lane];
    __syncthreads();                      // all waves done reading Wt
#pragma unroll
    for (int i = 0; i < 16; ++i)          // reuse Wt LDS as hid_T[m][t], stride 132
        Wt[lane * 132 + tl0 + i] = fmaxf(a1[i] + bb1, 0.f);
    __syncthreads();

    // MLP layer 2: one output per thread
    {
        const int to = tid >> 2, c = tid & 3;
        const float* w2 = W2 + c * HH;
        float a = 0.f;
        for (int m = 0; m < HH; ++m)
            a = fmaf(Wt[m * 132 + to], w2[m], a);   // bank (4m+to): conflict-free
        out[(size_t)(T0 + to) * 4 + c] = a + b2[c]; // coalesced
    }
}

extern "C" void kernel_launch(void* const* d_in, const int* in_sizes, int n_in,
                              void* d_out, int out_size, void* d_ws, size_t ws_size,
                              hipStream_t stream) {
    const float* emb  = (const float*)d_in[0];
    const float* W_ih = (const float*)d_in[1];
    const float* W_hh = (const float*)d_in[2];
    const float* b_ih = (const float*)d_in[3];
    const float* b_hh = (const float*)d_in[4];
    const float* W1   = (const float*)d_in[5];
    const float* b1   = (const float*)d_in[6];
    const float* W2   = (const float*)d_in[7];
    const float* b2   = (const float*)d_in[8];
    const int*   dn   = (const int*)d_in[9];

    float* gi  = (float*)d_ws;                         // 32768*192*4 = 25.2 MB
    float* W1T = (float*)d_ws + (size_t)NT * G3;       // 16 KB more
    float* o   = (float*)d_out;

    prep_kernel<<<NT / 64, 192, 0, stream>>>(emb, W_ih, b_ih, b_hh, W1, gi, W1T);
    gru_kernel<<<NT / 128, 512, 0, stream>>>(gi, W_hh, b_hh, b1, W2, b2, W1T, dn, o);
}